// Round 5
// baseline (154.576 us; speedup 1.0000x reference)
//
#include <hip/hip_runtime.h>
#include <math.h>

// Problem constants (fixed by reference): B=32, T=2048, D=128
constexpr int B  = 32;
constexpr int T  = 2048;
constexpr int D  = 128;
constexpr int CS = 8;            // timesteps per lane
constexpr int RT = 8;            // t-rows per wave
constexpr int BT = RT * CS;      // 64 timesteps per wave
constexpr int DQ = 32;           // d-columns per wave (8 lane-groups x 4)

// Fully autonomous wave: 64 lanes = 8 t-rows x 8 d-groups, lane owns 8 steps
// x 4 consecutive d. No __syncthreads, no allocated LDS, no inter-wave
// coupling -> no phase convoy (round-4 lesson: 3 barriers' worth of
// load/compute phase alignment held both pipes at <45%).
// Carry resolution: each lane computes per-chain {last-obs(v,t),
// first-obs(v,t), 8-bit mask} from its own registers; 8 broadcast shuffles
// share the packed masks; clz/ctz picks the source row; 2 dynamic shuffles
// per side fetch the summary. Row-0/row-7 lanes additionally probe a
// 16-step mask halo (coalesced int4). Serial global fallback only when a
// whole halo window is empty (P ~ 2^-16) -- exact reference semantics.
__global__ __launch_bounds__(256)
void interp_wave_kernel(const float* __restrict__ values,
                        const float* __restrict__ times,
                        const int*   __restrict__ mask,
                        float*       __restrict__ out)
{
    const int tid  = threadIdx.x;
    const int lane = tid & 63;
    const int row  = lane >> 3;            // 0..7 (t-row within wave)
    const int dg   = lane & 7;             // d-group within quarter
    const int waveId = (blockIdx.x << 2) + (tid >> 6);
    const int dq = waveId & 3;             // which quarter of D
    const int tb = (waveId >> 2) & 31;     // 64-step tile
    const int b  = waveId >> 7;

    const int d0  = dq * DQ + dg * 4;
    const int bt0 = tb * BT;
    const int t0  = bt0 + row * CS;

    const size_t bbase = (size_t)b * T * D;
    const float* vrow = values + bbase + (size_t)t0 * D + d0;
    const float* trow = times  + bbase + (size_t)t0 * D + d0;
    const int*   mrow = mask   + bbase + (size_t)t0 * D + d0;

    // ---- own tile: 24 independent wide loads (imm offsets i*512B) ----
    float vv[CS][4], tt[CS][4];
    unsigned mb[4] = {0u, 0u, 0u, 0u};
#pragma unroll
    for (int i = 0; i < CS; ++i) {
        const float4 a = *reinterpret_cast<const float4*>(vrow + i * D);
        const float4 s = *reinterpret_cast<const float4*>(trow + i * D);
        const int4   m = *reinterpret_cast<const int4*>(mrow + i * D);
        vv[i][0] = a.x; vv[i][1] = a.y; vv[i][2] = a.z; vv[i][3] = a.w;
        tt[i][0] = s.x; tt[i][1] = s.y; tt[i][2] = s.z; tt[i][3] = s.w;
        mb[0] |= (m.x != 0 ? 1u : 0u) << i;
        mb[1] |= (m.y != 0 ? 1u : 0u) << i;
        mb[2] |= (m.z != 0 ? 1u : 0u) << i;
        mb[3] |= (m.w != 0 ? 1u : 0u) << i;
    }

    // ---- halo probes: 16 steps before (row 0) / after (row 7) the tile ----
    unsigned pbp0 = 0u, pbp1 = 0u;         // chains {0,1} / {2,3}, 16 bits each
    unsigned nbp0 = 0u, nbp1 = 0u;
    if (row == 0 && tb > 0) {
#pragma unroll
        for (int k = 0; k < 16; ++k) {
            const int4 m = *reinterpret_cast<const int4*>(
                mask + bbase + (size_t)(bt0 - 16 + k) * D + d0);
            pbp0 |= (m.x != 0 ? 1u : 0u) << k;
            pbp0 |= (m.y != 0 ? 1u : 0u) << (16 + k);
            pbp1 |= (m.z != 0 ? 1u : 0u) << k;
            pbp1 |= (m.w != 0 ? 1u : 0u) << (16 + k);
        }
    }
    if (row == RT - 1 && tb < 31) {
#pragma unroll
        for (int k = 0; k < 16; ++k) {
            const int4 m = *reinterpret_cast<const int4*>(
                mask + bbase + (size_t)(bt0 + BT + k) * D + d0);
            nbp0 |= (m.x != 0 ? 1u : 0u) << k;
            nbp0 |= (m.y != 0 ? 1u : 0u) << (16 + k);
            nbp1 |= (m.z != 0 ? 1u : 0u) << k;
            nbp1 |= (m.w != 0 ? 1u : 0u) << (16 + k);
        }
    }

    // ---- per-row, per-chain summaries (register-only selects) ----
    float lv[4], lt[4], fv[4], ftm[4];
#pragma unroll
    for (int j = 0; j < 4; ++j) {
        float a = 0.f, c = 0.f, e = 0.f, g = 0.f;
#pragma unroll
        for (int i = 0; i < CS; ++i)
            if ((mb[j] >> i) & 1u) { a = vv[i][j]; c = tt[i][j]; }
#pragma unroll
        for (int i = CS - 1; i >= 0; --i)
            if ((mb[j] >> i) & 1u) { e = vv[i][j]; g = tt[i][j]; }
        lv[j] = a; lt[j] = c; fv[j] = e; ftm[j] = g;
    }
    const unsigned smP = (mb[0] & 0xFFu) | ((mb[1] & 0xFFu) << 8)
                       | ((mb[2] & 0xFFu) << 16) | ((mb[3] & 0xFFu) << 24);

    // ---- in-register exchange: broadcast all rows' packed masks ----
    unsigned allm[RT];
#pragma unroll
    for (int r = 0; r < RT; ++r)
        allm[r] = (unsigned)__shfl((int)smP, r * 8 + dg, 64);
    const unsigned pbs0 = (unsigned)__shfl((int)pbp0, dg, 64);       // from row 0
    const unsigned pbs1 = (unsigned)__shfl((int)pbp1, dg, 64);
    const unsigned nbs0 = (unsigned)__shfl((int)nbp0, 56 + dg, 64);  // from row 7
    const unsigned nbs1 = (unsigned)__shfl((int)nbp1, 56 + dg, 64);

    // ---- per chain: resolve carries, fill, interpolate (in-place in vv) ----
#pragma unroll
    for (int j = 0; j < 4; ++j) {
        const int d = d0 + j;
        unsigned rm = 0u;
#pragma unroll
        for (int r = 0; r < RT; ++r)
            rm |= (((allm[r] >> (8 * j)) & 0xFFu) ? 1u : 0u) << r;

        const unsigned below = rm & ((1u << row) - 1u);
        const unsigned above = rm >> (row + 1);

        // unconditional dynamic shuffles (uniform control flow)
        const int rs = below ? (31 - __builtin_clz(below)) : 0;
        const int rb = above ? (row + 1 + __builtin_ctz(above)) : 0;
        const float gLV = __shfl(lv[j],  rs * 8 + dg, 64);
        const float gLT = __shfl(lt[j],  rs * 8 + dg, 64);
        const float gFV = __shfl(fv[j],  rb * 8 + dg, 64);
        const float gFT = __shfl(ftm[j], rb * 8 + dg, 64);

        // forward carry
        float cfx, cft;
        if (below) { cfx = gLV; cft = gLT; }
        else {
            const unsigned pbj = ((j & 1) ? ((j < 2 ? pbs0 : pbs1) >> 16)
                                          :  (j < 2 ? pbs0 : pbs1)) & 0xFFFFu;
            if (pbj) {
                const int st = bt0 - 16 + (31 - __builtin_clz(pbj));
                const size_t o = bbase + (size_t)st * D + d;
                cfx = values[o]; cft = times[o];
            } else {
                bool found = false; cfx = 0.f; cft = 0.f;
                for (int st = bt0 - 17; st >= 0; --st) {        // ~never runs
                    if (mask[bbase + (size_t)st * D + d] != 0) {
                        const size_t o = bbase + (size_t)st * D + d;
                        cfx = values[o]; cft = times[o]; found = true; break;
                    }
                }
                if (!found) { cfx = 0.f; cft = times[bbase + d]; }  // ref init
            }
        }

        // backward carry
        float cbx, cbt;
        if (above) { cbx = gFV; cbt = gFT; }
        else {
            const unsigned nbj = ((j & 1) ? ((j < 2 ? nbs0 : nbs1) >> 16)
                                          :  (j < 2 ? nbs0 : nbs1)) & 0xFFFFu;
            if (nbj) {
                const int st = bt0 + BT + __builtin_ctz(nbj);
                const size_t o = bbase + (size_t)st * D + d;
                cbx = values[o]; cbt = times[o];
            } else {
                bool found = false; cbx = 0.f; cbt = 0.f;
                for (int st = bt0 + BT + 16; st < T; ++st) {    // ~never runs
                    if (mask[bbase + (size_t)st * D + d] != 0) {
                        const size_t o = bbase + (size_t)st * D + d;
                        cbx = values[o]; cbt = times[o]; found = true; break;
                    }
                }
                if (!found) { cbx = 0.f; cbt = times[bbase + (size_t)(T - 1) * D + d]; }
            }
        }

        // forward fill (includes current step, like reference cummax)
        float xl[CS], tl_[CS];
#pragma unroll
        for (int i = 0; i < CS; ++i) {
            if ((mb[j] >> i) & 1u) { cfx = vv[i][j]; cft = tt[i][j]; }
            xl[i] = cfx; tl_[i] = cft;
        }
        // reverse fill + interpolate; result written in place into vv
#pragma unroll
        for (int i = CS - 1; i >= 0; --i) {
            const bool obs = (mb[j] >> i) & 1u;
            if (obs) { cbx = vv[i][j]; cbt = tt[i][j]; }
            const float denom = cbt - tl_[i];
            const float num   = xl[i] * (cbt - tt[i][j]) + cbx * (tt[i][j] - tl_[i]);
            const bool  safe  = (denom != 0.f);
            float xi = num / (safe ? denom : 1.f);
            xi = (safe && isfinite(xi)) ? xi : 0.f;
            vv[i][j] = obs ? vv[i][j] : xi;
        }
    }

    // ---- wide stores ----
    float* orow = out + bbase + (size_t)t0 * D + d0;
#pragma unroll
    for (int i = 0; i < CS; ++i) {
        float4 o; o.x = vv[i][0]; o.y = vv[i][1]; o.z = vv[i][2]; o.w = vv[i][3];
        *reinterpret_cast<float4*>(orow + i * D) = o;
    }
}

extern "C" void kernel_launch(void* const* d_in, const int* in_sizes, int n_in,
                              void* d_out, int out_size, void* d_ws, size_t ws_size,
                              hipStream_t stream)
{
    const float* values = (const float*)d_in[0];
    const float* times  = (const float*)d_in[1];
    const int*   mask   = (const int*)d_in[2];
    float*       out    = (float*)d_out;

    // 32 b x 32 tiles x 4 d-quarters = 4096 waves = 1024 blocks of 256
    const int blocks = (B * (T / BT) * (D / DQ)) / 4;
    interp_wave_kernel<<<blocks, 256, 0, stream>>>(values, times, mask, out);
}

// Round 6
// 136.164 us; speedup vs baseline: 1.1352x; 1.1352x over previous
//
#include <hip/hip_runtime.h>
#include <math.h>

// Problem constants (fixed by reference): B=32, T=2048, D=128
constexpr int B  = 32;
constexpr int T  = 2048;
constexpr int D  = 128;
constexpr int CS = 4;            // timesteps per lane
constexpr int GW = 16;           // step-groups per wave
constexpr int WT = GW * CS;      // 64 timesteps per wave tile
constexpr int WD = 16;           // d-columns per wave (4 quads x 4)

// Wave-autonomous, ballot-exchange design.
//   wave = 64 lanes = 16 step-groups x 4 d-quads -> 64 steps x 16 d.
//   lane  = 4 steps x 4 consecutive d (R2's footprint: 12 wide loads,
//           short dependency chain; 8192 waves = full nominal occupancy).
// Exchange: per chain, ONE __ballot gives the 64-step group-occupancy mask;
// clz/ctz over column-strided bits picks the source lane; __shfl pulls its
// in-register {last/first-obs (v,t)} summary. No LDS, no barriers, no
// divergent probe loops. Tile-edge history: 16-step halo mask loaded
// cooperatively (1 int4/lane/side, perfectly coalesced) + 4 ballots;
// edge lanes gather (v,t) at the found index (L3-warm). Serial global
// fallback only when the whole halo is empty (P ~= 2^-16) -- exact
// reference semantics (defaults: x=0, t=times[b,0,d] / times[b,T-1,d]).
__global__ __launch_bounds__(256)
void interp_ballot_kernel(const float* __restrict__ values,
                          const float* __restrict__ times,
                          const int*   __restrict__ mask,
                          float*       __restrict__ out)
{
    const int tid  = threadIdx.x;
    const int lane = tid & 63;
    const int g    = lane >> 2;            // step-group 0..15
    const int q    = lane & 3;             // d-quad within the wave's 16 d

    const int waveId = (blockIdx.x << 2) | (tid >> 6);
    const int db   = waveId & 7;           // d-block of 16 (8 per b)
    const int tile = (waveId >> 3) & 31;   // 64-step tile (32 per b)
    const int b    = waveId >> 8;

    const int d0  = db * WD + q * 4;
    const int bt0 = tile * WT;
    const int t0  = bt0 + g * CS;

    const size_t bbase = (size_t)b * T * D;
    const float* vrow = values + bbase + (size_t)t0 * D + d0;
    const float* trow = times  + bbase + (size_t)t0 * D + d0;
    const int*   mrow = mask   + bbase + (size_t)t0 * D + d0;

    // ---- own tile: 12 independent wide loads (16 full lines per instr) ----
    float vv[CS][4], tt[CS][4];
    unsigned mb[4] = {0u, 0u, 0u, 0u};
#pragma unroll
    for (int i = 0; i < CS; ++i) {
        const float4 a = *reinterpret_cast<const float4*>(vrow + i * D);
        const float4 s = *reinterpret_cast<const float4*>(trow + i * D);
        const int4   m = *reinterpret_cast<const int4*>(mrow + i * D);
        vv[i][0] = a.x; vv[i][1] = a.y; vv[i][2] = a.z; vv[i][3] = a.w;
        tt[i][0] = s.x; tt[i][1] = s.y; tt[i][2] = s.z; tt[i][3] = s.w;
        mb[0] |= (m.x != 0 ? 1u : 0u) << i;
        mb[1] |= (m.y != 0 ? 1u : 0u) << i;
        mb[2] |= (m.z != 0 ? 1u : 0u) << i;
        mb[3] |= (m.w != 0 ? 1u : 0u) << i;
    }

    // ---- cooperative halo masks: lane loads ONE int4 per side ----
    // prev halo: steps [bt0-16, bt0), next halo: [bt0+WT, bt0+WT+16).
    // Lane covers (step offset g, quad q) -> same coalescing as own loads.
    unsigned long long hpb[4] = {0ull, 0ull, 0ull, 0ull};
    unsigned long long hnb[4] = {0ull, 0ull, 0ull, 0ull};
    if (tile > 0) {                        // wave-uniform branch
        const int4 m = *reinterpret_cast<const int4*>(
            mask + bbase + (size_t)(bt0 - 16 + g) * D + db * WD + q * 4);
        hpb[0] = __ballot(m.x != 0);
        hpb[1] = __ballot(m.y != 0);
        hpb[2] = __ballot(m.z != 0);
        hpb[3] = __ballot(m.w != 0);
    }
    if (tile < 31) {                       // wave-uniform branch
        const int4 m = *reinterpret_cast<const int4*>(
            mask + bbase + (size_t)(bt0 + WT + g) * D + db * WD + q * 4);
        hnb[0] = __ballot(m.x != 0);
        hnb[1] = __ballot(m.y != 0);
        hnb[2] = __ballot(m.z != 0);
        hnb[3] = __ballot(m.w != 0);
    }

    // ---- per-lane, per-chain summaries (register-only selects) ----
    float lv[4], lt[4], fv[4], ftm[4];
#pragma unroll
    for (int j = 0; j < 4; ++j) {
        float a = 0.f, c = 0.f, e = 0.f, h = 0.f;
#pragma unroll
        for (int i = 0; i < CS; ++i)
            if ((mb[j] >> i) & 1u) { a = vv[i][j]; c = tt[i][j]; }
#pragma unroll
        for (int i = CS - 1; i >= 0; --i)
            if ((mb[j] >> i) & 1u) { e = vv[i][j]; h = tt[i][j]; }
        lv[j] = a; lt[j] = c; fv[j] = e; ftm[j] = h;
    }

    // ---- ballot exchange: 64-step occupancy mask per chain, one instr ----
    unsigned long long gb[4];
#pragma unroll
    for (int j = 0; j < 4; ++j)
        gb[j] = __ballot(mb[j] != 0u);
    const unsigned long long colmask = 0x1111111111111111ull << q;

    // ---- per chain: resolve carries, fill, interpolate (in place) ----
#pragma unroll
    for (int j = 0; j < 4; ++j) {
        const int d = d0 + j;
        const unsigned long long col   = gb[j] & colmask;
        const unsigned long long below = col & ((1ull << lane) - 1ull);
        const unsigned long long above = col & ~((2ull << lane) - 1ull);

        // unconditional dynamic shuffles (uniform control flow)
        const int rsF = below ? (63 - __builtin_clzll(below)) : lane;
        const int rsB = above ? __builtin_ctzll(above) : lane;
        const float gLV = __shfl(lv[j],  rsF, 64);
        const float gLT = __shfl(lt[j],  rsF, 64);
        const float gFV = __shfl(fv[j],  rsB, 64);
        const float gFT = __shfl(ftm[j], rsB, 64);

        // forward carry
        float cfx, cft;
        if (below) { cfx = gLV; cft = gLT; }
        else {
            const unsigned long long hcol = hpb[j] & colmask;  // 0 when tile==0
            if (hcol) {
                const int st = bt0 - 16 + ((63 - __builtin_clzll(hcol)) >> 2);
                const size_t o = bbase + (size_t)st * D + d;
                cfx = values[o]; cft = times[o];
            } else {
                bool found = false; cfx = 0.f; cft = 0.f;
                for (int st = bt0 - 17; st >= 0; --st) {        // ~never runs
                    if (mask[bbase + (size_t)st * D + d] != 0) {
                        const size_t o = bbase + (size_t)st * D + d;
                        cfx = values[o]; cft = times[o]; found = true; break;
                    }
                }
                if (!found) { cfx = 0.f; cft = times[bbase + d]; }  // ref init
            }
        }

        // backward carry
        float cbx, cbt;
        if (above) { cbx = gFV; cbt = gFT; }
        else {
            const unsigned long long hcol = hnb[j] & colmask;  // 0 when tile==31
            if (hcol) {
                const int st = bt0 + WT + (__builtin_ctzll(hcol) >> 2);
                const size_t o = bbase + (size_t)st * D + d;
                cbx = values[o]; cbt = times[o];
            } else {
                bool found = false; cbx = 0.f; cbt = 0.f;
                for (int st = bt0 + WT + 16; st < T; ++st) {    // ~never runs
                    if (mask[bbase + (size_t)st * D + d] != 0) {
                        const size_t o = bbase + (size_t)st * D + d;
                        cbx = values[o]; cbt = times[o]; found = true; break;
                    }
                }
                if (!found) { cbx = 0.f; cbt = times[bbase + (size_t)(T - 1) * D + d]; }
            }
        }

        // forward fill (includes current step, like reference cummax)
        float xl[CS], tl_[CS];
#pragma unroll
        for (int i = 0; i < CS; ++i) {
            if ((mb[j] >> i) & 1u) { cfx = vv[i][j]; cft = tt[i][j]; }
            xl[i] = cfx; tl_[i] = cft;
        }
        // reverse fill + interpolate; result written in place into vv
#pragma unroll
        for (int i = CS - 1; i >= 0; --i) {
            const bool obs = (mb[j] >> i) & 1u;
            if (obs) { cbx = vv[i][j]; cbt = tt[i][j]; }
            const float denom = cbt - tl_[i];
            const float num   = xl[i] * (cbt - tt[i][j]) + cbx * (tt[i][j] - tl_[i]);
            const bool  safe  = (denom != 0.f);
            float xi = num / (safe ? denom : 1.f);
            xi = (safe && isfinite(xi)) ? xi : 0.f;
            vv[i][j] = obs ? vv[i][j] : xi;
        }
    }

    // ---- wide stores ----
    float* orow = out + bbase + (size_t)t0 * D + d0;
#pragma unroll
    for (int i = 0; i < CS; ++i) {
        float4 o; o.x = vv[i][0]; o.y = vv[i][1]; o.z = vv[i][2]; o.w = vv[i][3];
        *reinterpret_cast<float4*>(orow + i * D) = o;
    }
}

extern "C" void kernel_launch(void* const* d_in, const int* in_sizes, int n_in,
                              void* d_out, int out_size, void* d_ws, size_t ws_size,
                              hipStream_t stream)
{
    const float* values = (const float*)d_in[0];
    const float* times  = (const float*)d_in[1];
    const int*   mask   = (const int*)d_in[2];
    float*       out    = (float*)d_out;

    // 32 b x 32 tiles x 8 d-blocks = 8192 waves = 2048 blocks of 256
    const int blocks = (B * (T / WT) * (D / WD) * 64) / 256;
    interp_ballot_kernel<<<blocks, 256, 0, stream>>>(values, times, mask, out);
}